// Round 7
// baseline (3657.683 us; speedup 1.0000x reference)
//
#include <hip/hip_runtime.h>

// CNF: 16-step RK4, aug dynamics = 3-layer tanh MLP + exact trace via
//   tr[b] = s1^T (W2 .* G) s2,  G[j,k] = sum_i W1[i,j] W3[k,i]
// Persistent kernel: 256 blocks x 512 threads (8 waves), 16 samples/block.
// R6: s1 precomputed in stage 1 (s1bf LDS), C-matrix B-frags pinned in
// registers (256 VGPR/wave, halves stage-2 L2 traffic), swizzle fixed for
// row&8 collisions, dxp padded (stride 68), stage 3 on all 8 waves,
// loop-invariant biases hoisted.

#define NSTEP 16
#define TSAMP 16

typedef short v8s __attribute__((ext_vector_type(8)));
typedef float v4f __attribute__((ext_vector_type(4)));

__device__ __forceinline__ short bf16r(float x) {
    unsigned u = __builtin_bit_cast(unsigned, x);
    u = u + 0x7FFFu + ((u >> 16) & 1u);
    return (short)(u >> 16);
}
__device__ __forceinline__ float bf2f(short s) {
    unsigned u = ((unsigned)(unsigned short)s) << 16;
    return __builtin_bit_cast(float, u);
}
__device__ __forceinline__ float tanh_fast(float x) {
    float e = __expf(2.0f * x);
    return 1.0f - 2.0f / (e + 1.0f);
}
// rows r, r+4, r+8, r+12 map to 4 distinct 16B slots (2-way max = free)
__device__ __forceinline__ int swz(int row) {
    return ((row & 7) << 4) ^ ((row & 8) << 2);
}

// ws layout (shorts): W2s[262144] | Cs[262144] | W1s[32768] | W3s[32768]
// B-frag-linear layout: elem( tile=(ntile*NK+ks), lane, e ) =
//   Bmat[ ks*32 + (lane>>4)*8 + e ][ ntile*16 + (lane&15) ]
__global__ __launch_bounds__(256) void cnf_prep(
    const float* __restrict__ W1, const float* __restrict__ W2,
    const float* __restrict__ W3, short* __restrict__ ws)
{
  int t = blockIdx.x * 256 + threadIdx.x;
  short* W2s = ws;
  short* Cs  = ws + 262144;
  short* W1s = ws + 524288;
  short* W3s = ws + 557056;
  if (t < 32768) {           // W2s + Cs  (K=512, N=512, NK=16)
    int l = t & 63;
    int tk = t >> 6;
    int ks = tk & 15, ntile = tk >> 4;
    int n = ntile * 16 + (l & 15);
    int kbase = ks * 32 + (l >> 4) * 8;
    v8s wv, cv;
#pragma unroll
    for (int e = 0; e < 8; ++e) {
      int k = kbase + e;
      float w2 = W2[k * 512 + n];
      float g = 0.0f;
      for (int i = 0; i < 64; ++i)
        g += W1[i * 512 + k] * W3[n * 64 + i];
      wv[e] = bf16r(w2);
      cv[e] = bf16r(w2 * g);
    }
    ((v8s*)W2s)[t] = wv;
    ((v8s*)Cs)[t]  = cv;
  } else if (t < 36864) {    // W1s (x-part, K=64, N=512, NK=2)
    int u = t - 32768;
    int l = u & 63, tk = u >> 6;
    int ks = tk & 1, ntile = tk >> 1;
    int n = ntile * 16 + (l & 15);
    int kbase = ks * 32 + (l >> 4) * 8;
    v8s wv;
#pragma unroll
    for (int e = 0; e < 8; ++e)
      wv[e] = bf16r(W1[(kbase + e) * 512 + n]);
    ((v8s*)W1s)[u] = wv;
  } else if (t < 40960) {    // W3s (K=512, N=64, NK=16)
    int u = t - 36864;
    int l = u & 63, tk = u >> 6;
    int ks = tk & 15, ntile = tk >> 4;
    int n = ntile * 16 + (l & 15);
    int kbase = ks * 32 + (l >> 4) * 8;
    v8s wv;
#pragma unroll
    for (int e = 0; e < 8; ++e)
      wv[e] = bf16r(W3[(kbase + e) * 64 + n]);
    ((v8s*)W3s)[u] = wv;
  }
}

__global__ __launch_bounds__(512) void cnf_main(
    const float* __restrict__ x_in, const float* __restrict__ t_span,
    const float* __restrict__ W1, const float* __restrict__ b1,
    const float* __restrict__ b2, const float* __restrict__ b3,
    const short* __restrict__ ws, float* __restrict__ out)
{
  const int tid = threadIdx.x;
  const int lane = tid & 63;
  const int w = tid >> 6;           // wave 0..7, owns cols [w*64, w*64+64)
  const int l15 = lane & 15;
  const int l16 = lane >> 4;
  const int b0 = blockIdx.x * TSAMP;

  const short* W2s = ws;
  const short* Cs  = ws + 262144;
  const short* W1s = ws + 524288;
  const short* W3s = ws + 557056;

  __shared__ __align__(16) short xbf[16 * 64];    // stage input, bf16, swizzled
  __shared__ __align__(16) short h1bf[16 * 512];
  __shared__ __align__(16) short s1bf[16 * 512];  // 1-h1^2, written in stage 1
  __shared__ __align__(16) short h2bf[16 * 512];
  __shared__ __align__(16) float x0s[16 * 64];    // f32 state
  __shared__ __align__(16) float xas[16 * 64];    // RK4 accumulator
  __shared__ __align__(16) float dxp[8][16 * 68]; // padded stride 68
  __shared__ float trs[16];
  __shared__ float ld0s[16];
  __shared__ float ldas[16];

  // ---- pin C-matrix B-frags in registers (static indexing only)
  v8s creg[64];
#pragma unroll
  for (int u = 0; u < 64; ++u) {
    int nt = u >> 4, ks = u & 15;
    creg[u] = ((const v8s*)Cs)[((w * 4 + nt) * 16 + ks) * 64 + lane];
  }

  // ---- hoist loop-invariant biases
  float bias1v[4], w1tv[4], bias2v[4];
#pragma unroll
  for (int nt = 0; nt < 4; ++nt) {
    int col = (w * 4 + nt) * 16 + l15;
    bias1v[nt] = b1[col];
    w1tv[nt]   = W1[64 * 512 + col];
    bias2v[nt] = b2[col];
  }
  const float b3v = b3[tid & 63];   // both RK4 rows use the same col

  // prologue: load x tile, write bf16 swizzled stage input
  for (int i = tid; i < 1024; i += 512) {
    int row = i >> 6, col = i & 63;
    float v = x_in[(size_t)(b0 + row) * 64 + col];
    x0s[i] = v;
    int byte = (row * 128 + col * 2) ^ swz(row);
    *(short*)((char*)xbf + byte) = bf16r(v);
  }
  if (tid < 16) { ld0s[tid] = 0.0f; trs[tid] = 0.0f; }
  __syncthreads();

  const int sA = swz(l15);

  for (int step = 0; step < NSTEP; ++step) {
    float t0 = t_span[step];
    float dt = t_span[step + 1] - t0;
#pragma unroll 1
    for (int st = 0; st < 4; ++st) {
      float tc = (st == 0) ? t0 : ((st == 3) ? (t0 + dt) : (t0 + 0.5f * dt));

      // ---- stage 1: h1 = tanh(xs @ W1x + t*w1t + b1); also write s1
      {
        v8s ax[2];
#pragma unroll
        for (int ks = 0; ks < 2; ++ks)
          ax[ks] = *(const v8s*)((const char*)xbf +
                     ((l15 * 128 + ks * 64 + l16 * 16) ^ sA));
#pragma unroll
        for (int nt = 0; nt < 4; ++nt) {
          int ng = w * 4 + nt;
          v4f acc = {0.f, 0.f, 0.f, 0.f};
#pragma unroll
          for (int ks = 0; ks < 2; ++ks) {
            v8s b = ((const v8s*)W1s)[(ng * 2 + ks) * 64 + lane];
            acc = __builtin_amdgcn_mfma_f32_16x16x32_bf16(ax[ks], b, acc, 0, 0, 0);
          }
          float bias = bias1v[nt] + tc * w1tv[nt];
          int col = ng * 16 + l15;
#pragma unroll
          for (int r = 0; r < 4; ++r) {
            float h = tanh_fast(acc[r] + bias);
            int row = l16 * 4 + r;
            int byte = (row * 1024 + col * 2) ^ swz(row);
            *(short*)((char*)h1bf + byte) = bf16r(h);
            *(short*)((char*)s1bf + byte) = bf16r(1.0f - h * h);
          }
        }
      }
      __syncthreads();

      // ---- stage 2: h2pre = h1@W2 + b2 ; v = s1@C(reg) ; tr partial dot
      {
        v4f acc2[4] = {};
        v4f accv[4] = {};
#pragma unroll
        for (int ks = 0; ks < 16; ++ks) {
          int byte = (l15 * 1024 + ks * 64 + l16 * 16) ^ sA;
          v8s a1 = *(const v8s*)((const char*)h1bf + byte);
          v8s as = *(const v8s*)((const char*)s1bf + byte);
#pragma unroll
          for (int nt = 0; nt < 4; ++nt) {
            v8s bw = ((const v8s*)W2s)[((w * 4 + nt) * 16 + ks) * 64 + lane];
            acc2[nt] = __builtin_amdgcn_mfma_f32_16x16x32_bf16(a1, bw, acc2[nt], 0, 0, 0);
            accv[nt] = __builtin_amdgcn_mfma_f32_16x16x32_bf16(as, creg[nt * 16 + ks], accv[nt], 0, 0, 0);
          }
        }
        float trp[4] = {0.f, 0.f, 0.f, 0.f};
#pragma unroll
        for (int nt = 0; nt < 4; ++nt) {
          int col = (w * 4 + nt) * 16 + l15;
#pragma unroll
          for (int r = 0; r < 4; ++r) {
            float h = tanh_fast(acc2[nt][r] + bias2v[nt]);
            float s2 = 1.0f - h * h;
            int row = l16 * 4 + r;
            int byte = (row * 1024 + col * 2) ^ swz(row);
            *(short*)((char*)h2bf + byte) = bf16r(h);
            trp[r] += accv[nt][r] * s2;   // same frag layout: elementwise
          }
        }
#pragma unroll
        for (int m = 1; m < 16; m <<= 1) {
#pragma unroll
          for (int r = 0; r < 4; ++r)
            trp[r] += __shfl_xor(trp[r], m, 64);
        }
        if (l15 == 0) {
#pragma unroll
          for (int r = 0; r < 4; ++r)
            atomicAdd(&trs[l16 * 4 + r], trp[r]);
        }
      }
      __syncthreads();

      // ---- stage 3: dx = h2 @ W3 (K split over all 8 waves, 2 ks each)
      {
        v4f acc3[4] = {};
#pragma unroll
        for (int kk = 0; kk < 2; ++kk) {
          int ks = w * 2 + kk;
          v8s a = *(const v8s*)((const char*)h2bf +
                    ((l15 * 1024 + ks * 64 + l16 * 16) ^ sA));
#pragma unroll
          for (int nt = 0; nt < 4; ++nt) {
            v8s b = ((const v8s*)W3s)[(nt * 16 + ks) * 64 + lane];
            acc3[nt] = __builtin_amdgcn_mfma_f32_16x16x32_bf16(a, b, acc3[nt], 0, 0, 0);
          }
        }
#pragma unroll
        for (int nt = 0; nt < 4; ++nt)
#pragma unroll
          for (int r = 0; r < 4; ++r)
            dxp[w][(l16 * 4 + r) * 68 + nt * 16 + l15] = acc3[nt][r];
      }
      __syncthreads();

      // ---- RK4 update
      for (int i = tid; i < 1024; i += 512) {
        int row = i >> 6, col = i & 63;
        float dxv = b3v;
#pragma unroll
        for (int ww = 0; ww < 8; ++ww) dxv += dxp[ww][row * 68 + col];
        float x0v = x0s[i];
        float xsn;
        if (st == 0)      { xas[i] = x0v + (dt * (1.0f/6.0f)) * dxv; xsn = x0v + 0.5f * dt * dxv; }
        else if (st == 1) { xas[i] += (dt * (1.0f/3.0f)) * dxv;      xsn = x0v + 0.5f * dt * dxv; }
        else if (st == 2) { xas[i] += (dt * (1.0f/3.0f)) * dxv;      xsn = x0v + dt * dxv; }
        else              { float nx = xas[i] + (dt * (1.0f/6.0f)) * dxv; x0s[i] = nx; xsn = nx; }
        int byte = (row * 128 + col * 2) ^ swz(row);
        *(short*)((char*)xbf + byte) = bf16r(xsn);
      }
      if (tid < 16) {
        float kld = -trs[tid];
        trs[tid] = 0.0f;
        if (st == 0)      ldas[tid] = ld0s[tid] + (dt * (1.0f/6.0f)) * kld;
        else if (st == 3) ld0s[tid] = ldas[tid] + (dt * (1.0f/6.0f)) * kld;
        else              ldas[tid] += (dt * (1.0f/3.0f)) * kld;
      }
      __syncthreads();
    }
  }

  // epilogue: z then log_det, concatenated flat
  for (int i = tid; i < 1024; i += 512)
    out[(size_t)(b0 + (i >> 6)) * 64 + (i & 63)] = x0s[i];
  if (tid < 16)
    out[262144 + b0 + tid] = ld0s[tid];
}

extern "C" void kernel_launch(void* const* d_in, const int* in_sizes, int n_in,
                              void* d_out, int out_size, void* d_ws, size_t ws_size,
                              hipStream_t stream) {
  const float* x  = (const float*)d_in[0];
  const float* ts = (const float*)d_in[1];
  const float* W1 = (const float*)d_in[2];
  const float* b1 = (const float*)d_in[3];
  const float* W2 = (const float*)d_in[4];
  const float* b2 = (const float*)d_in[5];
  const float* W3 = (const float*)d_in[6];
  const float* b3 = (const float*)d_in[7];
  short* ws = (short*)d_ws;
  float* outp = (float*)d_out;

  hipLaunchKernelGGL(cnf_prep, dim3(160), dim3(256), 0, stream, W1, W2, W3, ws);
  hipLaunchKernelGGL(cnf_main, dim3(256), dim3(512), 0, stream,
                     x, ts, W1, b1, b2, b3, (const short*)ws, outp);
}

// Round 11
// 3487.243 us; speedup vs baseline: 1.0489x; 1.0489x over previous
//
#include <hip/hip_runtime.h>

// CNF: 16-step RK4, aug dynamics = 3-layer tanh MLP + exact trace via
//   tr[b] = s1^T (W2 .* G) s2,  G[j,k] = sum_i W1[i,j] W3[k,i]
// Persistent kernel: 256 blocks x 512 threads (8 waves), 16 samples/block.
// R8: C streamed from L2 (R6's creg spilled: 512-thrd blocks cap VGPR at 256,
// FETCH 7.4GB scratch traffic). Keep R6 wins: s1 precomputed in stage 1,
// hoisted biases, 8-wave stage 3, padded dxp, row&8-fixed swizzle.

#define NSTEP 16
#define TSAMP 16

typedef short v8s __attribute__((ext_vector_type(8)));
typedef float v4f __attribute__((ext_vector_type(4)));

__device__ __forceinline__ short bf16r(float x) {
    unsigned u = __builtin_bit_cast(unsigned, x);
    u = u + 0x7FFFu + ((u >> 16) & 1u);
    return (short)(u >> 16);
}
__device__ __forceinline__ float tanh_fast(float x) {
    float e = __expf(2.0f * x);
    return 1.0f - 2.0f / (e + 1.0f);
}
// rows r, r+4, r+8, r+12 map to 4 distinct 16B slots
__device__ __forceinline__ int swz(int row) {
    return ((row & 7) << 4) ^ ((row & 8) << 2);
}

// ws layout (shorts): W2s[262144] | Cs[262144] | W1s[32768] | W3s[32768]
// B-frag-linear layout: elem( tile=(ntile*NK+ks), lane, e ) =
//   Bmat[ ks*32 + (lane>>4)*8 + e ][ ntile*16 + (lane&15) ]
__global__ __launch_bounds__(256) void cnf_prep(
    const float* __restrict__ W1, const float* __restrict__ W2,
    const float* __restrict__ W3, short* __restrict__ ws)
{
  int t = blockIdx.x * 256 + threadIdx.x;
  short* W2s = ws;
  short* Cs  = ws + 262144;
  short* W1s = ws + 524288;
  short* W3s = ws + 557056;
  if (t < 32768) {           // W2s + Cs  (K=512, N=512, NK=16)
    int l = t & 63;
    int tk = t >> 6;
    int ks = tk & 15, ntile = tk >> 4;
    int n = ntile * 16 + (l & 15);
    int kbase = ks * 32 + (l >> 4) * 8;
    v8s wv, cv;
#pragma unroll
    for (int e = 0; e < 8; ++e) {
      int k = kbase + e;
      float w2 = W2[k * 512 + n];
      float g = 0.0f;
      for (int i = 0; i < 64; ++i)
        g += W1[i * 512 + k] * W3[n * 64 + i];
      wv[e] = bf16r(w2);
      cv[e] = bf16r(w2 * g);
    }
    ((v8s*)W2s)[t] = wv;
    ((v8s*)Cs)[t]  = cv;
  } else if (t < 36864) {    // W1s (x-part, K=64, N=512, NK=2)
    int u = t - 32768;
    int l = u & 63, tk = u >> 6;
    int ks = tk & 1, ntile = tk >> 1;
    int n = ntile * 16 + (l & 15);
    int kbase = ks * 32 + (l >> 4) * 8;
    v8s wv;
#pragma unroll
    for (int e = 0; e < 8; ++e)
      wv[e] = bf16r(W1[(kbase + e) * 512 + n]);
    ((v8s*)W1s)[u] = wv;
  } else if (t < 40960) {    // W3s (K=512, N=64, NK=16)
    int u = t - 36864;
    int l = u & 63, tk = u >> 6;
    int ks = tk & 15, ntile = tk >> 4;
    int n = ntile * 16 + (l & 15);
    int kbase = ks * 32 + (l >> 4) * 8;
    v8s wv;
#pragma unroll
    for (int e = 0; e < 8; ++e)
      wv[e] = bf16r(W3[(kbase + e) * 64 + n]);
    ((v8s*)W3s)[u] = wv;
  }
}

__global__ __launch_bounds__(512) void cnf_main(
    const float* __restrict__ x_in, const float* __restrict__ t_span,
    const float* __restrict__ W1, const float* __restrict__ b1,
    const float* __restrict__ b2, const float* __restrict__ b3,
    const short* __restrict__ ws, float* __restrict__ out)
{
  const int tid = threadIdx.x;
  const int lane = tid & 63;
  const int w = tid >> 6;           // wave 0..7, owns cols [w*64, w*64+64)
  const int l15 = lane & 15;
  const int l16 = lane >> 4;
  const int b0 = blockIdx.x * TSAMP;

  const short* W2s = ws;
  const short* Cs  = ws + 262144;
  const short* W1s = ws + 524288;
  const short* W3s = ws + 557056;

  __shared__ __align__(16) short xbf[16 * 64];    // stage input, bf16, swizzled
  __shared__ __align__(16) short h1bf[16 * 512];
  __shared__ __align__(16) short s1bf[16 * 512];  // 1-h1^2, written in stage 1
  __shared__ __align__(16) short h2bf[16 * 512];
  __shared__ __align__(16) float x0s[16 * 64];    // f32 state
  __shared__ __align__(16) float xas[16 * 64];    // RK4 accumulator
  __shared__ __align__(16) float dxp[8][16 * 68]; // padded stride 68
  __shared__ float trs[16];
  __shared__ float ld0s[16];
  __shared__ float ldas[16];

  // ---- hoist loop-invariant biases
  float bias1v[4], w1tv[4], bias2v[4];
#pragma unroll
  for (int nt = 0; nt < 4; ++nt) {
    int col = (w * 4 + nt) * 16 + l15;
    bias1v[nt] = b1[col];
    w1tv[nt]   = W1[64 * 512 + col];
    bias2v[nt] = b2[col];
  }
  const float b3v = b3[tid & 63];

  // prologue: load x tile, write bf16 swizzled stage input
  for (int i = tid; i < 1024; i += 512) {
    int row = i >> 6, col = i & 63;
    float v = x_in[(size_t)(b0 + row) * 64 + col];
    x0s[i] = v;
    int byte = (row * 128 + col * 2) ^ swz(row);
    *(short*)((char*)xbf + byte) = bf16r(v);
  }
  if (tid < 16) { ld0s[tid] = 0.0f; trs[tid] = 0.0f; }
  __syncthreads();

  const int sA = swz(l15);

  for (int step = 0; step < NSTEP; ++step) {
    float t0 = t_span[step];
    float dt = t_span[step + 1] - t0;
#pragma unroll 1
    for (int st = 0; st < 4; ++st) {
      float tc = (st == 0) ? t0 : ((st == 3) ? (t0 + dt) : (t0 + 0.5f * dt));

      // ---- stage 1: h1 = tanh(xs @ W1x + t*w1t + b1); also write s1
      {
        v8s ax[2];
#pragma unroll
        for (int ks = 0; ks < 2; ++ks)
          ax[ks] = *(const v8s*)((const char*)xbf +
                     ((l15 * 128 + ks * 64 + l16 * 16) ^ sA));
#pragma unroll
        for (int nt = 0; nt < 4; ++nt) {
          int ng = w * 4 + nt;
          v4f acc = {0.f, 0.f, 0.f, 0.f};
#pragma unroll
          for (int ks = 0; ks < 2; ++ks) {
            v8s b = ((const v8s*)W1s)[(ng * 2 + ks) * 64 + lane];
            acc = __builtin_amdgcn_mfma_f32_16x16x32_bf16(ax[ks], b, acc, 0, 0, 0);
          }
          float bias = bias1v[nt] + tc * w1tv[nt];
          int col = ng * 16 + l15;
#pragma unroll
          for (int r = 0; r < 4; ++r) {
            float h = tanh_fast(acc[r] + bias);
            int row = l16 * 4 + r;
            int byte = (row * 1024 + col * 2) ^ swz(row);
            *(short*)((char*)h1bf + byte) = bf16r(h);
            *(short*)((char*)s1bf + byte) = bf16r(1.0f - h * h);
          }
        }
      }
      __syncthreads();

      // ---- stage 2: h2pre = h1@W2 + b2 ; v = s1@C ; tr partial dot
      {
        v4f acc2[4] = {};
        v4f accv[4] = {};
#pragma unroll
        for (int ks = 0; ks < 16; ++ks) {
          int byte = (l15 * 1024 + ks * 64 + l16 * 16) ^ sA;
          v8s a1 = *(const v8s*)((const char*)h1bf + byte);
          v8s as = *(const v8s*)((const char*)s1bf + byte);
#pragma unroll
          for (int nt = 0; nt < 4; ++nt) {
            v8s bw = ((const v8s*)W2s)[((w * 4 + nt) * 16 + ks) * 64 + lane];
            v8s bc = ((const v8s*)Cs)[((w * 4 + nt) * 16 + ks) * 64 + lane];
            acc2[nt] = __builtin_amdgcn_mfma_f32_16x16x32_bf16(a1, bw, acc2[nt], 0, 0, 0);
            accv[nt] = __builtin_amdgcn_mfma_f32_16x16x32_bf16(as, bc, accv[nt], 0, 0, 0);
          }
        }
        float trp[4] = {0.f, 0.f, 0.f, 0.f};
#pragma unroll
        for (int nt = 0; nt < 4; ++nt) {
          int col = (w * 4 + nt) * 16 + l15;
#pragma unroll
          for (int r = 0; r < 4; ++r) {
            float h = tanh_fast(acc2[nt][r] + bias2v[nt]);
            float s2 = 1.0f - h * h;
            int row = l16 * 4 + r;
            int byte = (row * 1024 + col * 2) ^ swz(row);
            *(short*)((char*)h2bf + byte) = bf16r(h);
            trp[r] += accv[nt][r] * s2;   // same frag layout: elementwise
          }
        }
#pragma unroll
        for (int m = 1; m < 16; m <<= 1) {
#pragma unroll
          for (int r = 0; r < 4; ++r)
            trp[r] += __shfl_xor(trp[r], m, 64);
        }
        if (l15 == 0) {
#pragma unroll
          for (int r = 0; r < 4; ++r)
            atomicAdd(&trs[l16 * 4 + r], trp[r]);
        }
      }
      __syncthreads();

      // ---- stage 3: dx = h2 @ W3 (K split over all 8 waves, 2 ks each)
      {
        v4f acc3[4] = {};
#pragma unroll
        for (int kk = 0; kk < 2; ++kk) {
          int ks = w * 2 + kk;
          v8s a = *(const v8s*)((const char*)h2bf +
                    ((l15 * 1024 + ks * 64 + l16 * 16) ^ sA));
#pragma unroll
          for (int nt = 0; nt < 4; ++nt) {
            v8s b = ((const v8s*)W3s)[(nt * 16 + ks) * 64 + lane];
            acc3[nt] = __builtin_amdgcn_mfma_f32_16x16x32_bf16(a, b, acc3[nt], 0, 0, 0);
          }
        }
#pragma unroll
        for (int nt = 0; nt < 4; ++nt)
#pragma unroll
          for (int r = 0; r < 4; ++r)
            dxp[w][(l16 * 4 + r) * 68 + nt * 16 + l15] = acc3[nt][r];
      }
      __syncthreads();

      // ---- RK4 update
      for (int i = tid; i < 1024; i += 512) {
        int row = i >> 6, col = i & 63;
        float dxv = b3v;
#pragma unroll
        for (int ww = 0; ww < 8; ++ww) dxv += dxp[ww][row * 68 + col];
        float x0v = x0s[i];
        float xsn;
        if (st == 0)      { xas[i] = x0v + (dt * (1.0f/6.0f)) * dxv; xsn = x0v + 0.5f * dt * dxv; }
        else if (st == 1) { xas[i] += (dt * (1.0f/3.0f)) * dxv;      xsn = x0v + 0.5f * dt * dxv; }
        else if (st == 2) { xas[i] += (dt * (1.0f/3.0f)) * dxv;      xsn = x0v + dt * dxv; }
        else              { float nx = xas[i] + (dt * (1.0f/6.0f)) * dxv; x0s[i] = nx; xsn = nx; }
        int byte = (row * 128 + col * 2) ^ swz(row);
        *(short*)((char*)xbf + byte) = bf16r(xsn);
      }
      if (tid < 16) {
        float kld = -trs[tid];
        trs[tid] = 0.0f;
        if (st == 0)      ldas[tid] = ld0s[tid] + (dt * (1.0f/6.0f)) * kld;
        else if (st == 3) ld0s[tid] = ldas[tid] + (dt * (1.0f/6.0f)) * kld;
        else              ldas[tid] += (dt * (1.0f/3.0f)) * kld;
      }
      __syncthreads();
    }
  }

  // epilogue: z then log_det, concatenated flat
  for (int i = tid; i < 1024; i += 512)
    out[(size_t)(b0 + (i >> 6)) * 64 + (i & 63)] = x0s[i];
  if (tid < 16)
    out[262144 + b0 + tid] = ld0s[tid];
}

extern "C" void kernel_launch(void* const* d_in, const int* in_sizes, int n_in,
                              void* d_out, int out_size, void* d_ws, size_t ws_size,
                              hipStream_t stream) {
  const float* x  = (const float*)d_in[0];
  const float* ts = (const float*)d_in[1];
  const float* W1 = (const float*)d_in[2];
  const float* b1 = (const float*)d_in[3];
  const float* W2 = (const float*)d_in[4];
  const float* b2 = (const float*)d_in[5];
  const float* W3 = (const float*)d_in[6];
  const float* b3 = (const float*)d_in[7];
  short* ws = (short*)d_ws;
  float* outp = (float*)d_out;

  hipLaunchKernelGGL(cnf_prep, dim3(160), dim3(256), 0, stream, W1, W2, W3, ws);
  hipLaunchKernelGGL(cnf_main, dim3(256), dim3(512), 0, stream,
                     x, ts, W1, b1, b2, b3, (const short*)ws, outp);
}

// Round 12
// 837.483 us; speedup vs baseline: 4.3675x; 4.1640x over previous
//
#include <hip/hip_runtime.h>

// CNF: 16-step RK4, aug dynamics = 3-layer tanh MLP + exact trace via
//   tr[b] = s1^T (W2 .* G) s2,  G[j,k] = sum_i W1[i,j] W3[k,i]
// Persistent kernel: 256 blocks x 512 threads (8 waves), 16 samples/block.
// R12 = exact R5 base (verified 891us, clean traffic) + ONE delta:
// s1=1-h1^2 precomputed in stage 1 into LDS aliased over dxp's storage
// (disjoint lifetimes), replacing the per-ks in-register derivation
// (~640 VALU ops/wave/eval). LDS stays 59904B; no other changes.

#define NSTEP 16
#define TSAMP 16

typedef short v8s __attribute__((ext_vector_type(8)));
typedef float v4f __attribute__((ext_vector_type(4)));

__device__ __forceinline__ short bf16r(float x) {
    unsigned u = __builtin_bit_cast(unsigned, x);
    u = u + 0x7FFFu + ((u >> 16) & 1u);
    return (short)(u >> 16);
}
__device__ __forceinline__ float tanh_fast(float x) {
    float e = __expf(2.0f * x);
    return 1.0f - 2.0f / (e + 1.0f);
}

// ws layout (shorts): W2s[262144] | Cs[262144] | W1s[32768] | W3s[32768]
// B-frag-linear layout: elem( tile=(ntile*NK+ks), lane, e ) =
//   Bmat[ ks*32 + (lane>>4)*8 + e ][ ntile*16 + (lane&15) ]
__global__ __launch_bounds__(256) void cnf_prep(
    const float* __restrict__ W1, const float* __restrict__ W2,
    const float* __restrict__ W3, short* __restrict__ ws)
{
  int t = blockIdx.x * 256 + threadIdx.x;
  short* W2s = ws;
  short* Cs  = ws + 262144;
  short* W1s = ws + 524288;
  short* W3s = ws + 557056;
  if (t < 32768) {           // W2s + Cs  (K=512, N=512, NK=16)
    int l = t & 63;
    int tk = t >> 6;
    int ks = tk & 15, ntile = tk >> 4;
    int n = ntile * 16 + (l & 15);
    int kbase = ks * 32 + (l >> 4) * 8;
    v8s wv, cv;
#pragma unroll
    for (int e = 0; e < 8; ++e) {
      int k = kbase + e;
      float w2 = W2[k * 512 + n];
      float g = 0.0f;
      for (int i = 0; i < 64; ++i)
        g += W1[i * 512 + k] * W3[n * 64 + i];
      wv[e] = bf16r(w2);
      cv[e] = bf16r(w2 * g);
    }
    ((v8s*)W2s)[t] = wv;
    ((v8s*)Cs)[t]  = cv;
  } else if (t < 36864) {    // W1s (x-part, K=64, N=512, NK=2)
    int u = t - 32768;
    int l = u & 63, tk = u >> 6;
    int ks = tk & 1, ntile = tk >> 1;
    int n = ntile * 16 + (l & 15);
    int kbase = ks * 32 + (l >> 4) * 8;
    v8s wv;
#pragma unroll
    for (int e = 0; e < 8; ++e)
      wv[e] = bf16r(W1[(kbase + e) * 512 + n]);
    ((v8s*)W1s)[u] = wv;
  } else if (t < 40960) {    // W3s (K=512, N=64, NK=16)
    int u = t - 36864;
    int l = u & 63, tk = u >> 6;
    int ks = tk & 15, ntile = tk >> 4;
    int n = ntile * 16 + (l & 15);
    int kbase = ks * 32 + (l >> 4) * 8;
    v8s wv;
#pragma unroll
    for (int e = 0; e < 8; ++e)
      wv[e] = bf16r(W3[(kbase + e) * 64 + n]);
    ((v8s*)W3s)[u] = wv;
  }
}

__global__ __launch_bounds__(512) void cnf_main(
    const float* __restrict__ x_in, const float* __restrict__ t_span,
    const float* __restrict__ W1, const float* __restrict__ b1,
    const float* __restrict__ b2, const float* __restrict__ b3,
    const short* __restrict__ ws, float* __restrict__ out)
{
  const int tid = threadIdx.x;
  const int lane = tid & 63;
  const int w = tid >> 6;           // wave 0..7, owns cols [w*64, w*64+64)
  const int l15 = lane & 15;
  const int l16 = lane >> 4;
  const int b0 = blockIdx.x * TSAMP;

  const short* W2s = ws;
  const short* Cs  = ws + 262144;
  const short* W1s = ws + 524288;
  const short* W3s = ws + 557056;

  __shared__ __align__(16) short xbf[16 * 64];    // stage input, bf16, XOR-swizzled
  __shared__ __align__(16) short h1bf[16 * 512];
  __shared__ __align__(16) short h2bf[16 * 512];
  __shared__ __align__(16) float x0s[16 * 64];    // f32 state
  __shared__ __align__(16) float xas[16 * 64];    // RK4 accumulator
  // s1bf (stage1->stage2) and dxp (stage3->RK4) have disjoint lifetimes,
  // separated by __syncthreads(): alias them over the same 16KB.
  __shared__ __align__(16) char sdx[16 * 512 * 2];
  __shared__ float trs[16];
  __shared__ float ld0s[16];
  __shared__ float ldas[16];

  short* s1bf = (short*)sdx;                    // [16*512] bf16, swizzled
  float (*dxp)[16 * 64] = (float (*)[16 * 64])sdx; // [4][1024] f32

  // prologue: load x tile, write bf16 swizzled stage input
  for (int i = tid; i < 1024; i += 512) {
    int row = i >> 6, col = i & 63;
    float v = x_in[(size_t)(b0 + row) * 64 + col];
    x0s[i] = v;
    int byte = row * 128 + col * 2;
    byte ^= (row & 7) << 4;
    *(short*)((char*)xbf + byte) = bf16r(v);
  }
  if (tid < 16) { ld0s[tid] = 0.0f; trs[tid] = 0.0f; }
  __syncthreads();

  for (int step = 0; step < NSTEP; ++step) {
    float t0 = t_span[step];
    float dt = t_span[step + 1] - t0;
#pragma unroll 1
    for (int st = 0; st < 4; ++st) {
      float tc = (st == 0) ? t0 : ((st == 3) ? (t0 + dt) : (t0 + 0.5f * dt));

      // ---- stage 1: h1 = tanh(xs @ W1x + t*w1t + b1); also write s1=1-h^2
#pragma unroll
      for (int nt = 0; nt < 4; ++nt) {
        int ng = w * 4 + nt;
        v4f acc = {0.f, 0.f, 0.f, 0.f};
#pragma unroll
        for (int ks = 0; ks < 2; ++ks) {
          int byte = l15 * 128 + ks * 64 + l16 * 16;
          byte ^= (l15 & 7) << 4;
          v8s a = *(const v8s*)((const char*)xbf + byte);
          v8s b = ((const v8s*)W1s)[(ng * 2 + ks) * 64 + lane];
          acc = __builtin_amdgcn_mfma_f32_16x16x32_bf16(a, b, acc, 0, 0, 0);
        }
        int col = ng * 16 + l15;
        float bias = b1[col] + tc * W1[64 * 512 + col];
#pragma unroll
        for (int r = 0; r < 4; ++r) {
          float h = tanh_fast(acc[r] + bias);
          int row = l16 * 4 + r;
          int byte = row * 1024 + col * 2;
          byte ^= (row & 7) << 4;
          *(short*)((char*)h1bf + byte) = bf16r(h);
          *(short*)((char*)s1bf + byte) = bf16r(1.0f - h * h);
        }
      }
      __syncthreads();

      // ---- stage 2: h2pre = h1@W2 + b2 ; v = s1@C ; tr partial dot
      {
        v4f acc2[4] = {};
        v4f accv[4] = {};
        for (int ks = 0; ks < 16; ++ks) {
          int byte = l15 * 1024 + ks * 64 + l16 * 16;
          byte ^= (l15 & 7) << 4;
          v8s a1 = *(const v8s*)((const char*)h1bf + byte);
          v8s as = *(const v8s*)((const char*)s1bf + byte);
#pragma unroll
          for (int nt = 0; nt < 4; ++nt) {
            int ng = w * 4 + nt;
            v8s bw = ((const v8s*)W2s)[(ng * 16 + ks) * 64 + lane];
            v8s bc = ((const v8s*)Cs)[(ng * 16 + ks) * 64 + lane];
            acc2[nt] = __builtin_amdgcn_mfma_f32_16x16x32_bf16(a1, bw, acc2[nt], 0, 0, 0);
            accv[nt] = __builtin_amdgcn_mfma_f32_16x16x32_bf16(as, bc, accv[nt], 0, 0, 0);
          }
        }
        float trp[4] = {0.f, 0.f, 0.f, 0.f};
#pragma unroll
        for (int nt = 0; nt < 4; ++nt) {
          int col = w * 64 + nt * 16 + l15;
          float bias = b2[col];
#pragma unroll
          for (int r = 0; r < 4; ++r) {
            float h = tanh_fast(acc2[nt][r] + bias);
            float s2 = 1.0f - h * h;
            int row = l16 * 4 + r;
            int byte = row * 1024 + col * 2;
            byte ^= (row & 7) << 4;
            *(short*)((char*)h2bf + byte) = bf16r(h);
            trp[r] += accv[nt][r] * s2;   // same frag layout: elementwise
          }
        }
#pragma unroll
        for (int m = 1; m < 16; m <<= 1) {
#pragma unroll
          for (int r = 0; r < 4; ++r)
            trp[r] += __shfl_xor(trp[r], m, 64);
        }
        if (l15 == 0) {
#pragma unroll
          for (int r = 0; r < 4; ++r)
            atomicAdd(&trs[l16 * 4 + r], trp[r]);
        }
      }
      __syncthreads();

      // ---- stage 3: dx = h2 @ W3 (K split over waves 0..3)
      if (w < 4) {
        v4f acc3[4] = {};
#pragma unroll
        for (int kk = 0; kk < 4; ++kk) {
          int ks = w * 4 + kk;
          int byte = l15 * 1024 + ks * 64 + l16 * 16;
          byte ^= (l15 & 7) << 4;
          v8s a = *(const v8s*)((const char*)h2bf + byte);
#pragma unroll
          for (int nt = 0; nt < 4; ++nt) {
            v8s b = ((const v8s*)W3s)[(nt * 16 + ks) * 64 + lane];
            acc3[nt] = __builtin_amdgcn_mfma_f32_16x16x32_bf16(a, b, acc3[nt], 0, 0, 0);
          }
        }
#pragma unroll
        for (int nt = 0; nt < 4; ++nt)
#pragma unroll
          for (int r = 0; r < 4; ++r)
            dxp[w][(l16 * 4 + r) * 64 + nt * 16 + l15] = acc3[nt][r];
      }
      __syncthreads();

      // ---- RK4 update
      for (int i = tid; i < 1024; i += 512) {
        int row = i >> 6, col = i & 63;
        float dxv = b3[col];
#pragma unroll
        for (int ww = 0; ww < 4; ++ww) dxv += dxp[ww][i];
        float x0v = x0s[i];
        float xsn;
        if (st == 0)      { xas[i] = x0v + (dt * (1.0f/6.0f)) * dxv; xsn = x0v + 0.5f * dt * dxv; }
        else if (st == 1) { xas[i] += (dt * (1.0f/3.0f)) * dxv;      xsn = x0v + 0.5f * dt * dxv; }
        else if (st == 2) { xas[i] += (dt * (1.0f/3.0f)) * dxv;      xsn = x0v + dt * dxv; }
        else              { float nx = xas[i] + (dt * (1.0f/6.0f)) * dxv; x0s[i] = nx; xsn = nx; }
        int byte = row * 128 + col * 2;
        byte ^= (row & 7) << 4;
        *(short*)((char*)xbf + byte) = bf16r(xsn);
      }
      if (tid < 16) {
        float kld = -trs[tid];
        trs[tid] = 0.0f;
        if (st == 0)      ldas[tid] = ld0s[tid] + (dt * (1.0f/6.0f)) * kld;
        else if (st == 3) ld0s[tid] = ldas[tid] + (dt * (1.0f/6.0f)) * kld;
        else              ldas[tid] += (dt * (1.0f/3.0f)) * kld;
      }
      __syncthreads();
    }
  }

  // epilogue: z then log_det, concatenated flat
  for (int i = tid; i < 1024; i += 512)
    out[(size_t)(b0 + (i >> 6)) * 64 + (i & 63)] = x0s[i];
  if (tid < 16)
    out[262144 + b0 + tid] = ld0s[tid];
}

extern "C" void kernel_launch(void* const* d_in, const int* in_sizes, int n_in,
                              void* d_out, int out_size, void* d_ws, size_t ws_size,
                              hipStream_t stream) {
  const float* x  = (const float*)d_in[0];
  const float* ts = (const float*)d_in[1];
  const float* W1 = (const float*)d_in[2];
  const float* b1 = (const float*)d_in[3];
  const float* W2 = (const float*)d_in[4];
  const float* b2 = (const float*)d_in[5];
  const float* W3 = (const float*)d_in[6];
  const float* b3 = (const float*)d_in[7];
  short* ws = (short*)d_ws;
  float* outp = (float*)d_out;

  hipLaunchKernelGGL(cnf_prep, dim3(160), dim3(256), 0, stream, W1, W2, W3, ws);
  hipLaunchKernelGGL(cnf_main, dim3(256), dim3(512), 0, stream,
                     x, ts, W1, b1, b2, b3, (const short*)ws, outp);
}